// Round 3
// baseline (942.741 us; speedup 1.0000x reference)
//
#include <hip/hip_runtime.h>
#include <hip/hip_bf16.h>

#define B_  64
#define T_  30
#define E_  300
#define H_  512
#define FD_ 512
#define V_  10000

typedef __attribute__((ext_vector_type(8))) unsigned short ushort8_t;
typedef __attribute__((ext_vector_type(4))) unsigned short ushort4_t;
typedef __attribute__((ext_vector_type(8))) __bf16 bf16x8;
typedef __attribute__((ext_vector_type(4))) float f32x4;

__device__ __forceinline__ float b2f(unsigned short u) {
    union { unsigned int i; float f; } v;
    v.i = ((unsigned int)u) << 16;
    return v.f;
}
__device__ __forceinline__ unsigned short f2b(float f) {
    unsigned int x = __builtin_bit_cast(unsigned int, f);
    unsigned int r = x + 0x7FFFu + ((x >> 16) & 1u);
    return (unsigned short)(r >> 16);
}

__device__ __forceinline__ f32x4 mfma16(bf16x8 a, bf16x8 b, f32x4 c) {
    return __builtin_amdgcn_mfma_f32_16x16x32_bf16(a, b, c, 0, 0, 0);
}

// ---------------- transpose+convert: src f32 [R][C] -> dst bf16 [C][ldDst]
struct TPtrs {
    const float* src[12];
    unsigned short* dst[12];
};

__global__ __launch_bounds__(256) void transpose_k(TPtrs tp, int R, int C, int ldDst) {
    const float* __restrict__ src = tp.src[blockIdx.z];
    unsigned short* __restrict__ dst = tp.dst[blockIdx.z];
    __shared__ unsigned short tile[32][33];
    const int tid = threadIdx.x;
    const int tc = tid & 31, tr = tid >> 5;   // tr 0..7
    const int c0 = blockIdx.x * 32, r0 = blockIdx.y * 32;
#pragma unroll
    for (int i = 0; i < 4; ++i) {
        int r = r0 + tr + i * 8, c = c0 + tc;
        unsigned short v = 0;
        if (r < R && c < C) v = f2b(src[(size_t)r * C + c]);
        tile[tr + i * 8][tc] = v;
    }
    __syncthreads();
#pragma unroll
    for (int i = 0; i < 4; ++i) {
        int c = c0 + tr + i * 8;  // dst row
        int r = r0 + tc;          // dst col
        if (c < C && r < R) dst[(size_t)c * ldDst + r] = tile[tc][tr + i * 8];
    }
}

// ---------------- f32 -> bf16 copy (h0)
__global__ __launch_bounds__(256) void f2b_k(const float* __restrict__ src,
                                             unsigned short* __restrict__ dst, int n) {
    int i = blockIdx.x * 256 + threadIdx.x;
    if (i < n) dst[i] = f2b(src[i]);
}

// ---------------- build X: X[t*B + b][e] (stride 304) = t==0 ? features[b][e] : B_emb[captions[b][t-1]][e]
__global__ __launch_bounds__(256) void build_x(const int* __restrict__ captions,
                                               const float* __restrict__ features,
                                               const float* __restrict__ Bemb,
                                               unsigned short* __restrict__ X) {
    int idx = blockIdx.x * 256 + threadIdx.x;     // over B_*T_*E_
    if (idx >= B_ * T_ * E_) return;
    int r = idx / E_, e = idx - r * E_;
    int t = r >> 6, b = r & 63;                   // r = t*B + b, B=64
    float v;
    if (t == 0) v = features[b * E_ + e];
    else {
        int tok = captions[b * T_ + (t - 1)];
        v = Bemb[(size_t)tok * E_ + e];
    }
    X[(size_t)r * 304 + e] = f2b(v);
}

// ---------------- generic bf16 MFMA GEMM: C[M][N] = A[M][K](lda) @ Bt[N][K](ldb)^T + bias(f32)
// batched over blockIdx.z via pointer table. Output dtype: outF32 ? float : bf16.
// Optional output-row permute (projection): orow = (r % permB)*permT + r/permB
struct GemmB4 {
    const unsigned short* A[4];
    const unsigned short* Bt[4];
    const float* bias[4];
    void* C[4];
};

__global__ __launch_bounds__(256) void gemm_k(GemmB4 ga, int M, int N, int K,
                                              int lda, int ldb, int permB, int permT,
                                              int outF32) {
    const int g = blockIdx.z;
    const unsigned short* __restrict__ A = ga.A[g];
    const unsigned short* __restrict__ Bt = ga.Bt[g];
    const float* __restrict__ bias = ga.bias[g];
    void* __restrict__ C = ga.C[g];

    const int m0 = blockIdx.y * 64, n0 = blockIdx.x * 64;
    __shared__ unsigned short As[64 * 40];
    __shared__ unsigned short Bs[64 * 40];
    const int tid = threadIdx.x;
    const int lane = tid & 63, wv = tid >> 6;
    const int quad = lane >> 4, l16 = lane & 15;
    const int mw = (wv & 1) * 32, nw = (wv >> 1) * 32;
    const int srow = tid >> 2, scol = (tid & 3) * 8;

    f32x4 acc[2][2] = {};

    for (int k0 = 0; k0 < K; k0 += 32) {
        const int kk = k0 + scol;
        {
            ushort8_t v = {0, 0, 0, 0, 0, 0, 0, 0};
            int gm = m0 + srow;
            if (gm < M) {
                const unsigned short* p = A + (size_t)gm * lda + kk;
                if (kk + 8 <= K) v = *(const ushort8_t*)p;
                else {
#pragma unroll
                    for (int j = 0; j < 8; ++j) if (kk + j < K) v[j] = p[j];
                }
            }
            *(ushort8_t*)&As[srow * 40 + scol] = v;
        }
        {
            ushort8_t v = {0, 0, 0, 0, 0, 0, 0, 0};
            int gn = n0 + srow;
            if (gn < N) {
                const unsigned short* p = Bt + (size_t)gn * ldb + kk;
                if (kk + 8 <= K) v = *(const ushort8_t*)p;
                else {
#pragma unroll
                    for (int j = 0; j < 8; ++j) if (kk + j < K) v[j] = p[j];
                }
            }
            *(ushort8_t*)&Bs[srow * 40 + scol] = v;
        }
        __syncthreads();
        bf16x8 af0 = *(const bf16x8*)&As[(mw + l16) * 40 + quad * 8];
        bf16x8 af1 = *(const bf16x8*)&As[(mw + 16 + l16) * 40 + quad * 8];
        bf16x8 bf0 = *(const bf16x8*)&Bs[(nw + l16) * 40 + quad * 8];
        bf16x8 bf1 = *(const bf16x8*)&Bs[(nw + 16 + l16) * 40 + quad * 8];
        acc[0][0] = mfma16(af0, bf0, acc[0][0]);
        acc[0][1] = mfma16(af0, bf1, acc[0][1]);
        acc[1][0] = mfma16(af1, bf0, acc[1][0]);
        acc[1][1] = mfma16(af1, bf1, acc[1][1]);
        __syncthreads();
    }

#pragma unroll
    for (int mt = 0; mt < 2; ++mt)
#pragma unroll
        for (int nt = 0; nt < 2; ++nt) {
            int col = n0 + nw + nt * 16 + l16;
            if (col >= N) continue;
            float bv = bias[col];
            int rowb = m0 + mw + mt * 16 + quad * 4;
#pragma unroll
            for (int r = 0; r < 4; ++r) {
                int rr = rowb + r;
                if (rr < M) {
                    float vv = acc[mt][nt][r] + bv;
                    int orow = permT ? ((rr % permB) * permT + rr / permB) : rr;
                    if (outF32) ((float*)C)[(size_t)orow * N + col] = vv;
                    else ((unsigned short*)C)[(size_t)orow * N + col] = f2b(vv);
                }
            }
        }
}

// ---------------- one LSTM step. Grid = 8 WGs (each owns 64 H-columns).
// Swapped MFMA orientation: D[hcol][b] = sum_k Wt[hcol][k] * h[b][k]  (A=Wt tile, B=h tile)
struct StepA {
    const unsigned short* h_prev;   // [B_][H_] bf16
    const unsigned short* Wt[4];    // [H_][H_], Wt[n][k] = W[k][n]
    const float* Wb[4];             // [H_] f32
    const unsigned short* U[4];     // pre-offset to t: [B_][H_] bf16
    const float* c0;                // [B_][H_] f32 (input)
    float* c_state;                 // [B_][H_] f32
    unsigned short* h_out;          // [B_][H_] bf16
    int first;
};

__global__ __launch_bounds__(256) void lstm_step(StepA s) {
    const int j = blockIdx.x;                 // H-column block
    __shared__ unsigned short Hs[64 * 40];
    __shared__ unsigned short Ws[4][64 * 40];
    const int tid = threadIdx.x;
    const int lane = tid & 63, wv = tid >> 6;
    const int quad = lane >> 4, l16 = lane & 15;
    const int mw = (wv & 1) * 32, nw = (wv >> 1) * 32;  // mw: hcol, nw: b
    const int srow = tid >> 2, scol = (tid & 3) * 8;

    f32x4 acc[4][2][2] = {};

    for (int k0 = 0; k0 < H_; k0 += 32) {
        *(ushort8_t*)&Hs[srow * 40 + scol] =
            *(const ushort8_t*)&s.h_prev[(size_t)srow * H_ + k0 + scol];
#pragma unroll
        for (int g = 0; g < 4; ++g)
            *(ushort8_t*)&Ws[g][srow * 40 + scol] =
                *(const ushort8_t*)&s.Wt[g][(size_t)(j * 64 + srow) * H_ + k0 + scol];
        __syncthreads();
        bf16x8 hb0 = *(const bf16x8*)&Hs[(nw + l16) * 40 + quad * 8];
        bf16x8 hb1 = *(const bf16x8*)&Hs[(nw + 16 + l16) * 40 + quad * 8];
#pragma unroll
        for (int g = 0; g < 4; ++g) {
            bf16x8 wa0 = *(const bf16x8*)&Ws[g][(mw + l16) * 40 + quad * 8];
            bf16x8 wa1 = *(const bf16x8*)&Ws[g][(mw + 16 + l16) * 40 + quad * 8];
            acc[g][0][0] = mfma16(wa0, hb0, acc[g][0][0]);
            acc[g][0][1] = mfma16(wa0, hb1, acc[g][0][1]);
            acc[g][1][0] = mfma16(wa1, hb0, acc[g][1][0]);
            acc[g][1][1] = mfma16(wa1, hb1, acc[g][1][1]);
        }
        __syncthreads();
    }

#pragma unroll
    for (int mt = 0; mt < 2; ++mt)
#pragma unroll
        for (int nt = 0; nt < 2; ++nt) {
            const int hc = j * 64 + mw + mt * 16 + quad * 4;   // 4 consecutive H cols
            const int b = nw + nt * 16 + l16;
            const size_t off = (size_t)b * H_ + hc;
            ushort4_t ui = *(const ushort4_t*)&s.U[0][off];
            ushort4_t uf = *(const ushort4_t*)&s.U[1][off];
            ushort4_t uo = *(const ushort4_t*)&s.U[2][off];
            ushort4_t uc = *(const ushort4_t*)&s.U[3][off];
            f32x4 wbi = *(const f32x4*)&s.Wb[0][hc];
            f32x4 wbf = *(const f32x4*)&s.Wb[1][hc];
            f32x4 wbo = *(const f32x4*)&s.Wb[2][hc];
            f32x4 wbc = *(const f32x4*)&s.Wb[3][hc];
            f32x4 cold;
            if (s.first) cold = *(const f32x4*)&s.c0[off];
            else cold = *(const f32x4*)&s.c_state[off];
            f32x4 cnew;
            ushort4_t hnew;
#pragma unroll
            for (int r = 0; r < 4; ++r) {
                float pi = acc[0][mt][nt][r] + b2f(ui[r]) + wbi[r];
                float pf = acc[1][mt][nt][r] + b2f(uf[r]) + wbf[r];
                float po = acc[2][mt][nt][r] + b2f(uo[r]) + wbo[r];
                float pc = acc[3][mt][nt][r] + b2f(uc[r]) + wbc[r];
                float it = 1.f / (1.f + __expf(-pi));
                float ft = 1.f / (1.f + __expf(-pf));
                float ot = 1.f / (1.f + __expf(-po));
                float ct = tanhf(pc);
                float cn = ft * cold[r] + it * ct;
                float hn = ot * cn;
                cnew[r] = cn;
                hnew[r] = f2b(hn);
            }
            *(f32x4*)&s.c_state[off] = cnew;
            *(ushort4_t*)&s.h_out[off] = hnew;
        }
}

extern "C" void kernel_launch(void* const* d_in, const int* in_sizes, int n_in,
                              void* d_out, int out_size, void* d_ws, size_t ws_size,
                              hipStream_t stream) {
    (void)in_sizes; (void)n_in; (void)out_size; (void)ws_size;
    const int* captions = (const int*)d_in[0];
    const float* features = (const float*)d_in[1];
    const float* h0 = (const float*)d_in[2];
    const float* c0 = (const float*)d_in[3];
    const float* Bemb = (const float*)d_in[4];
    const float *iVW[4], *iVb[4], *iSW[4], *iSb[4], *iUW[4], *iUb[4], *iWW[4], *iWb[4];
    for (int g = 0; g < 4; ++g) {
        const int base = 5 + 8 * g;
        iVW[g] = (const float*)d_in[base + 0];
        iVb[g] = (const float*)d_in[base + 1];
        iSW[g] = (const float*)d_in[base + 2];
        iSb[g] = (const float*)d_in[base + 3];
        iUW[g] = (const float*)d_in[base + 4];
        iUb[g] = (const float*)d_in[base + 5];
        iWW[g] = (const float*)d_in[base + 6];
        iWb[g] = (const float*)d_in[base + 7];
    }
    const float* CW = (const float*)d_in[37];
    const float* Cb = (const float*)d_in[38];

    // ---- workspace carve-up (bytes, 256B aligned)
    char* w = (char*)d_ws;
    auto alloc = [&](size_t bytes) -> void* {
        void* p = (void*)w;
        w += (bytes + 255) & ~(size_t)255;
        return p;
    };
    unsigned short* cH0 = (unsigned short*)alloc((size_t)B_ * H_ * 2);
    unsigned short *wVt[4], *wSt[4], *wUt[4], *wWt[4];
    for (int g = 0; g < 4; ++g) wVt[g] = (unsigned short*)alloc((size_t)FD_ * 304 * 2);
    for (int g = 0; g < 4; ++g) wSt[g] = (unsigned short*)alloc((size_t)FD_ * FD_ * 2);
    for (int g = 0; g < 4; ++g) wUt[g] = (unsigned short*)alloc((size_t)H_ * FD_ * 2);
    for (int g = 0; g < 4; ++g) wWt[g] = (unsigned short*)alloc((size_t)H_ * H_ * 2);
    unsigned short* wCt = (unsigned short*)alloc((size_t)V_ * H_ * 2);
    unsigned short* wX = (unsigned short*)alloc((size_t)B_ * T_ * 304 * 2);
    unsigned short *bufA[4], *bufB[4];
    for (int g = 0; g < 4; ++g) bufA[g] = (unsigned short*)alloc((size_t)B_ * T_ * FD_ * 2);
    for (int g = 0; g < 4; ++g) bufB[g] = (unsigned short*)alloc((size_t)B_ * T_ * FD_ * 2);
    unsigned short* Hall = (unsigned short*)alloc((size_t)B_ * T_ * H_ * 2);
    float* cst = (float*)alloc((size_t)B_ * H_ * 4);

    // ---- h0 -> bf16
    f2b_k<<<dim3((B_ * H_ + 255) / 256), 256, 0, stream>>>(h0, cH0, B_ * H_);

    // ---- transposes (f32 -> bf16)
    {
        TPtrs tp{};
        for (int g = 0; g < 4; ++g) {
            tp.src[g * 3 + 0] = iSW[g]; tp.dst[g * 3 + 0] = wSt[g];
            tp.src[g * 3 + 1] = iUW[g]; tp.dst[g * 3 + 1] = wUt[g];
            tp.src[g * 3 + 2] = iWW[g]; tp.dst[g * 3 + 2] = wWt[g];
        }
        transpose_k<<<dim3(16, 16, 12), 256, 0, stream>>>(tp, 512, 512, 512);
    }
    {
        TPtrs tp{};
        for (int g = 0; g < 4; ++g) { tp.src[g] = iVW[g]; tp.dst[g] = wVt[g]; }
        transpose_k<<<dim3(16, 10, 4), 256, 0, stream>>>(tp, E_, FD_, 304);
    }
    {
        TPtrs tp{};
        tp.src[0] = CW; tp.dst[0] = wCt;
        transpose_k<<<dim3(313, 16, 1), 256, 0, stream>>>(tp, H_, V_, H_);
    }

    // ---- build X (time-major rows r = t*B+b, stride 304)
    build_x<<<dim3((B_ * T_ * E_ + 255) / 256), 256, 0, stream>>>(captions, features, Bemb, wX);

    // ---- gate preactivation chain (batched over 4 gates)
    {
        GemmB4 ga;
        for (int g = 0; g < 4; ++g) { ga.A[g] = wX; ga.Bt[g] = wVt[g]; ga.bias[g] = iVb[g]; ga.C[g] = bufA[g]; }
        gemm_k<<<dim3(8, 30, 4), 256, 0, stream>>>(ga, B_ * T_, FD_, E_, 304, 304, 0, 0, 0);
    }
    {
        GemmB4 ga;
        for (int g = 0; g < 4; ++g) { ga.A[g] = bufA[g]; ga.Bt[g] = wSt[g]; ga.bias[g] = iSb[g]; ga.C[g] = bufB[g]; }
        gemm_k<<<dim3(8, 30, 4), 256, 0, stream>>>(ga, B_ * T_, FD_, FD_, FD_, FD_, 0, 0, 0);
    }
    {
        GemmB4 ga;
        for (int g = 0; g < 4; ++g) { ga.A[g] = bufB[g]; ga.Bt[g] = wUt[g]; ga.bias[g] = iUb[g]; ga.C[g] = bufA[g]; }
        gemm_k<<<dim3(8, 30, 4), 256, 0, stream>>>(ga, B_ * T_, H_, FD_, FD_, FD_, 0, 0, 0);
    }

    // ---- 30 sequential LSTM steps
    for (int t = 0; t < T_; ++t) {
        StepA sa;
        sa.h_prev = (t == 0) ? cH0 : (Hall + (size_t)(t - 1) * B_ * H_);
        for (int g = 0; g < 4; ++g) {
            sa.Wt[g] = wWt[g];
            sa.Wb[g] = iWb[g];
            sa.U[g] = bufA[g] + (size_t)t * B_ * H_;
        }
        sa.c0 = c0;
        sa.c_state = cst;
        sa.h_out = Hall + (size_t)t * B_ * H_;
        sa.first = (t == 0) ? 1 : 0;
        lstm_step<<<dim3(8), 256, 0, stream>>>(sa);
    }

    // ---- vocab projection for all (t,b), f32 output, permuting rows back to [B][T][V]
    {
        GemmB4 ga{};
        ga.A[0] = Hall; ga.Bt[0] = wCt; ga.bias[0] = Cb; ga.C[0] = d_out;
        gemm_k<<<dim3((V_ + 63) / 64, (B_ * T_) / 64, 1), 256, 0, stream>>>(
            ga, B_ * T_, V_, H_, H_, H_, B_, T_, 1);
    }
}

// Round 4
// 719.788 us; speedup vs baseline: 1.3097x; 1.3097x over previous
//
#include <hip/hip_runtime.h>
#include <hip/hip_bf16.h>

#define B_  64
#define T_  30
#define E_  300
#define H_  512
#define FD_ 512
#define V_  10000
#define NWG_FUSED 32

typedef __attribute__((ext_vector_type(8))) unsigned short ushort8_t;
typedef __attribute__((ext_vector_type(4))) unsigned short ushort4_t;
typedef __attribute__((ext_vector_type(8))) __bf16 bf16x8;
typedef __attribute__((ext_vector_type(4))) float f32x4;

__device__ __forceinline__ float b2f(unsigned short u) {
    union { unsigned int i; float f; } v;
    v.i = ((unsigned int)u) << 16;
    return v.f;
}
__device__ __forceinline__ unsigned short f2b(float f) {
    unsigned int x = __builtin_bit_cast(unsigned int, f);
    unsigned int r = x + 0x7FFFu + ((x >> 16) & 1u);
    return (unsigned short)(r >> 16);
}

__device__ __forceinline__ f32x4 mfma16(bf16x8 a, bf16x8 b, f32x4 c) {
    return __builtin_amdgcn_mfma_f32_16x16x32_bf16(a, b, c, 0, 0, 0);
}

// ---------------- barrier counter init (runs first on the stream each call)
__global__ void init_bar(int* bar) { if (threadIdx.x == 0) *bar = 0; }

// ---------------- transpose+convert: src f32 [R][C] -> dst bf16 [C][ldDst]
struct TPtrs {
    const float* src[12];
    unsigned short* dst[12];
};

__global__ __launch_bounds__(256) void transpose_k(TPtrs tp, int R, int C, int ldDst) {
    const float* __restrict__ src = tp.src[blockIdx.z];
    unsigned short* __restrict__ dst = tp.dst[blockIdx.z];
    __shared__ unsigned short tile[32][33];
    const int tid = threadIdx.x;
    const int tc = tid & 31, tr = tid >> 5;   // tr 0..7
    const int c0 = blockIdx.x * 32, r0 = blockIdx.y * 32;
#pragma unroll
    for (int i = 0; i < 4; ++i) {
        int r = r0 + tr + i * 8, c = c0 + tc;
        unsigned short v = 0;
        if (r < R && c < C) v = f2b(src[(size_t)r * C + c]);
        tile[tr + i * 8][tc] = v;
    }
    __syncthreads();
#pragma unroll
    for (int i = 0; i < 4; ++i) {
        int c = c0 + tr + i * 8;  // dst row
        int r = r0 + tc;          // dst col
        if (c < C && r < R) dst[(size_t)c * ldDst + r] = tile[tc][tr + i * 8];
    }
}

// ---------------- f32 -> bf16 copy (h0)
__global__ __launch_bounds__(256) void f2b_k(const float* __restrict__ src,
                                             unsigned short* __restrict__ dst, int n) {
    int i = blockIdx.x * 256 + threadIdx.x;
    if (i < n) dst[i] = f2b(src[i]);
}

// ---------------- build X: X[t*B + b][e] (stride 304) = t==0 ? features[b][e] : B_emb[captions[b][t-1]][e]
__global__ __launch_bounds__(256) void build_x(const int* __restrict__ captions,
                                               const float* __restrict__ features,
                                               const float* __restrict__ Bemb,
                                               unsigned short* __restrict__ X) {
    int idx = blockIdx.x * 256 + threadIdx.x;     // over B_*T_*E_
    if (idx >= B_ * T_ * E_) return;
    int r = idx / E_, e = idx - r * E_;
    int t = r >> 6, b = r & 63;                   // r = t*B + b, B=64
    float v;
    if (t == 0) v = features[b * E_ + e];
    else {
        int tok = captions[b * T_ + (t - 1)];
        v = Bemb[(size_t)tok * E_ + e];
    }
    X[(size_t)r * 304 + e] = f2b(v);
}

// ---------------- 128x128 MFMA GEMM: C[M][N] = A[M][K](lda) @ Bt[N][K](ldb)^T + bias(f32)
// batched over blockIdx.z via pointer table. outF32 selects output dtype.
// Optional output-row permute (projection): orow = (r % permB)*permT + r/permB
struct GemmB4 {
    const unsigned short* A[4];
    const unsigned short* Bt[4];
    const float* bias[4];
    void* C[4];
};

__global__ __launch_bounds__(256) void gemm_k(GemmB4 ga, int M, int N, int K,
                                              int lda, int ldb, int permB, int permT,
                                              int outF32) {
    const int g = blockIdx.z;
    const unsigned short* __restrict__ A = ga.A[g];
    const unsigned short* __restrict__ Bt = ga.Bt[g];
    const float* __restrict__ bias = ga.bias[g];
    void* __restrict__ C = ga.C[g];

    const int m0 = blockIdx.y * 128, n0 = blockIdx.x * 128;
    __shared__ unsigned short As[128 * 40];
    __shared__ unsigned short Bs[128 * 40];
    const int tid = threadIdx.x;
    const int lane = tid & 63, wv = tid >> 6;
    const int quad = lane >> 4, l16 = lane & 15;
    const int mw = (wv & 1) * 64, nw = (wv >> 1) * 64;
    const int srow = tid >> 2, scol = (tid & 3) * 8;   // srow 0..63, scol 0..24

    f32x4 acc[4][4] = {};

    for (int k0 = 0; k0 < K; k0 += 32) {
        const int kk = k0 + scol;
#pragma unroll
        for (int half = 0; half < 2; ++half) {
            const int row = srow + half * 64;
            {
                ushort8_t v = {0, 0, 0, 0, 0, 0, 0, 0};
                int gm = m0 + row;
                if (gm < M) {
                    const unsigned short* p = A + (size_t)gm * lda + kk;
                    if (kk + 8 <= K) v = *(const ushort8_t*)p;
                    else {
#pragma unroll
                        for (int jj = 0; jj < 8; ++jj) if (kk + jj < K) v[jj] = p[jj];
                    }
                }
                *(ushort8_t*)&As[row * 40 + scol] = v;
            }
            {
                ushort8_t v = {0, 0, 0, 0, 0, 0, 0, 0};
                int gn = n0 + row;
                if (gn < N) {
                    const unsigned short* p = Bt + (size_t)gn * ldb + kk;
                    if (kk + 8 <= K) v = *(const ushort8_t*)p;
                    else {
#pragma unroll
                        for (int jj = 0; jj < 8; ++jj) if (kk + jj < K) v[jj] = p[jj];
                    }
                }
                *(ushort8_t*)&Bs[row * 40 + scol] = v;
            }
        }
        __syncthreads();
        bf16x8 af[4], bf[4];
#pragma unroll
        for (int mt = 0; mt < 4; ++mt)
            af[mt] = *(const bf16x8*)&As[(mw + mt * 16 + l16) * 40 + quad * 8];
#pragma unroll
        for (int nt = 0; nt < 4; ++nt)
            bf[nt] = *(const bf16x8*)&Bs[(nw + nt * 16 + l16) * 40 + quad * 8];
#pragma unroll
        for (int mt = 0; mt < 4; ++mt)
#pragma unroll
            for (int nt = 0; nt < 4; ++nt)
                acc[mt][nt] = mfma16(af[mt], bf[nt], acc[mt][nt]);
        __syncthreads();
    }

#pragma unroll
    for (int mt = 0; mt < 4; ++mt)
#pragma unroll
        for (int nt = 0; nt < 4; ++nt) {
            int col = n0 + nw + nt * 16 + l16;
            if (col >= N) continue;
            float bv = bias[col];
            int rowb = m0 + mw + mt * 16 + quad * 4;
#pragma unroll
            for (int r = 0; r < 4; ++r) {
                int rr = rowb + r;
                if (rr < M) {
                    float vv = acc[mt][nt][r] + bv;
                    int orow = permT ? ((rr % permB) * permT + rr / permB) : rr;
                    if (outF32) ((float*)C)[(size_t)orow * N + col] = vv;
                    else ((unsigned short*)C)[(size_t)orow * N + col] = f2b(vv);
                }
            }
        }
}

// ---------------- fused persistent LSTM: all 30 steps in one launch.
// Grid = 32 WGs x 256. WG j owns h-cols [j*16, j*16+16). Wave g (=tid>>6) owns gate g.
// Gate-weight A-fragments live in VGPRs (loaded once). c state lives in registers.
// h round-trips through global (Hall) with a monotonic-counter grid barrier per step.
struct FusedA {
    const unsigned short* h0;     // [B_][H_] bf16
    const unsigned short* Wt[4];  // [H_][H_] bf16, Wt[n][k] = W[k][n]
    const float* Wb[4];           // [H_] f32
    const unsigned short* U[4];   // [T_*B_][H_] bf16 (chain output, incl. U bias)
    const float* c0;              // [B_][H_] f32
    unsigned short* Hall;         // [T_*B_][H_] bf16 out
    int* bar;
};

__global__ __launch_bounds__(256, 1) void lstm_fused(FusedA s) {
    const int j = blockIdx.x;                 // 0..31
    const int tid = threadIdx.x;
    const int g = tid >> 6;                   // wave = gate
    const int lane = tid & 63;
    const int quad = lane >> 4, l16 = lane & 15;
    __shared__ float xch[4][16 * 65];         // [gate][hc_local][batch], padded

    // one-time: gate-g A-fragments for this WG's 16 h-cols (16 k-chunks)
    bf16x8 afrag[16];
    {
        const unsigned short* wt = s.Wt[g] + (size_t)(j * 16 + l16) * H_ + quad * 8;
#pragma unroll
        for (int kc = 0; kc < 16; ++kc)
            afrag[kc] = *(const bf16x8*)(wt + kc * 32);
    }

    // per-thread epilogue assignment: (batch eb, local hcols ehc..ehc+3)
    const int eb = tid >> 2;
    const int ehc = (tid & 3) * 4;
    const int hcg = j * 16 + ehc;             // global hcol base
    f32x4 wb[4];
#pragma unroll
    for (int q = 0; q < 4; ++q) wb[q] = *(const f32x4*)(s.Wb[q] + hcg);
    f32x4 c = *(const f32x4*)(s.c0 + (size_t)eb * H_ + hcg);

    for (int t = 0; t < T_; ++t) {
        const unsigned short* hp = (t == 0) ? s.h0 : (s.Hall + (size_t)(t - 1) * B_ * H_);
        // GEMM: D[hc(16) x b(64)] for gate g, K=512
        f32x4 acc[4] = {{0.f,0.f,0.f,0.f},{0.f,0.f,0.f,0.f},{0.f,0.f,0.f,0.f},{0.f,0.f,0.f,0.f}};
#pragma unroll
        for (int kc = 0; kc < 16; ++kc) {
            const unsigned short* hb = hp + kc * 32 + quad * 8;
#pragma unroll
            for (int nt = 0; nt < 4; ++nt) {
                bf16x8 bfr = *(const bf16x8*)(hb + (size_t)(nt * 16 + l16) * H_);
                acc[nt] = mfma16(afrag[kc], bfr, acc[nt]);
            }
        }
        // exchange gate preacts through LDS
#pragma unroll
        for (int nt = 0; nt < 4; ++nt)
#pragma unroll
            for (int r = 0; r < 4; ++r)
                xch[g][(quad * 4 + r) * 65 + nt * 16 + l16] = acc[nt][r];
        __syncthreads();
        // epilogue: this thread's 4 elements (eb, ehc..+3)
        ushort4_t u[4];
#pragma unroll
        for (int q = 0; q < 4; ++q)
            u[q] = *(const ushort4_t*)(s.U[q] + ((size_t)t * B_ + eb) * H_ + hcg);
        ushort4_t hnew;
#pragma unroll
        for (int r = 0; r < 4; ++r) {
            float pi = xch[0][(ehc + r) * 65 + eb] + b2f(u[0][r]) + wb[0][r];
            float pf = xch[1][(ehc + r) * 65 + eb] + b2f(u[1][r]) + wb[1][r];
            float po = xch[2][(ehc + r) * 65 + eb] + b2f(u[2][r]) + wb[2][r];
            float pc = xch[3][(ehc + r) * 65 + eb] + b2f(u[3][r]) + wb[3][r];
            float it = 1.f / (1.f + __expf(-pi));
            float ft = 1.f / (1.f + __expf(-pf));
            float ot = 1.f / (1.f + __expf(-po));
            float ct = tanhf(pc);
            float cn = ft * c[r] + it * ct;
            c[r] = cn;
            hnew[r] = f2b(ot * cn);
        }
        *(ushort4_t*)(s.Hall + ((size_t)t * B_ + eb) * H_ + hcg) = hnew;
        // grid barrier (monotonic counter; RMW spin so poll always hits coherence point)
        __syncthreads();                          // all lanes wrote h & finished xch reads
        if (tid == 0) {
            __threadfence();                      // release h device-wide
            atomicAdd(s.bar, 1);
            const int target = NWG_FUSED * (t + 1);
            while (atomicAdd(s.bar, 0) < target) __builtin_amdgcn_s_sleep(1);
            __threadfence();                      // acquire remote h
        }
        __syncthreads();
    }
}

extern "C" void kernel_launch(void* const* d_in, const int* in_sizes, int n_in,
                              void* d_out, int out_size, void* d_ws, size_t ws_size,
                              hipStream_t stream) {
    (void)in_sizes; (void)n_in; (void)out_size; (void)ws_size;
    const int* captions = (const int*)d_in[0];
    const float* features = (const float*)d_in[1];
    const float* h0 = (const float*)d_in[2];
    const float* c0 = (const float*)d_in[3];
    const float* Bemb = (const float*)d_in[4];
    const float *iVW[4], *iVb[4], *iSW[4], *iSb[4], *iUW[4], *iUb[4], *iWW[4], *iWb[4];
    for (int g = 0; g < 4; ++g) {
        const int base = 5 + 8 * g;
        iVW[g] = (const float*)d_in[base + 0];
        iVb[g] = (const float*)d_in[base + 1];
        iSW[g] = (const float*)d_in[base + 2];
        iSb[g] = (const float*)d_in[base + 3];
        iUW[g] = (const float*)d_in[base + 4];
        iUb[g] = (const float*)d_in[base + 5];
        iWW[g] = (const float*)d_in[base + 6];
        iWb[g] = (const float*)d_in[base + 7];
    }
    const float* CW = (const float*)d_in[37];
    const float* Cb = (const float*)d_in[38];

    // ---- workspace carve-up (bytes, 256B aligned)
    char* w = (char*)d_ws;
    auto alloc = [&](size_t bytes) -> void* {
        void* p = (void*)w;
        w += (bytes + 255) & ~(size_t)255;
        return p;
    };
    int* dbar = (int*)alloc(256);
    unsigned short* cH0 = (unsigned short*)alloc((size_t)B_ * H_ * 2);
    unsigned short *wVt[4], *wSt[4], *wUt[4], *wWt[4];
    for (int g = 0; g < 4; ++g) wVt[g] = (unsigned short*)alloc((size_t)FD_ * 304 * 2);
    for (int g = 0; g < 4; ++g) wSt[g] = (unsigned short*)alloc((size_t)FD_ * FD_ * 2);
    for (int g = 0; g < 4; ++g) wUt[g] = (unsigned short*)alloc((size_t)H_ * FD_ * 2);
    for (int g = 0; g < 4; ++g) wWt[g] = (unsigned short*)alloc((size_t)H_ * H_ * 2);
    unsigned short* wCt = (unsigned short*)alloc((size_t)V_ * H_ * 2);
    unsigned short* wX = (unsigned short*)alloc((size_t)B_ * T_ * 304 * 2);
    unsigned short *bufA[4], *bufB[4];
    for (int g = 0; g < 4; ++g) bufA[g] = (unsigned short*)alloc((size_t)B_ * T_ * FD_ * 2);
    for (int g = 0; g < 4; ++g) bufB[g] = (unsigned short*)alloc((size_t)B_ * T_ * FD_ * 2);
    unsigned short* Hall = (unsigned short*)alloc((size_t)B_ * T_ * H_ * 2);

    // ---- barrier init + h0 -> bf16
    init_bar<<<dim3(1), 64, 0, stream>>>(dbar);
    f2b_k<<<dim3((B_ * H_ + 255) / 256), 256, 0, stream>>>(h0, cH0, B_ * H_);

    // ---- transposes (f32 -> bf16)
    {
        TPtrs tp{};
        for (int g = 0; g < 4; ++g) {
            tp.src[g * 3 + 0] = iSW[g]; tp.dst[g * 3 + 0] = wSt[g];
            tp.src[g * 3 + 1] = iUW[g]; tp.dst[g * 3 + 1] = wUt[g];
            tp.src[g * 3 + 2] = iWW[g]; tp.dst[g * 3 + 2] = wWt[g];
        }
        transpose_k<<<dim3(16, 16, 12), 256, 0, stream>>>(tp, 512, 512, 512);
    }
    {
        TPtrs tp{};
        for (int g = 0; g < 4; ++g) { tp.src[g] = iVW[g]; tp.dst[g] = wVt[g]; }
        transpose_k<<<dim3(16, 10, 4), 256, 0, stream>>>(tp, E_, FD_, 304);
    }
    {
        TPtrs tp{};
        tp.src[0] = CW; tp.dst[0] = wCt;
        transpose_k<<<dim3(313, 16, 1), 256, 0, stream>>>(tp, H_, V_, H_);
    }

    // ---- build X (time-major rows r = t*B+b, stride 304)
    build_x<<<dim3((B_ * T_ * E_ + 255) / 256), 256, 0, stream>>>(captions, features, Bemb, wX);

    // ---- gate preactivation chain (batched over 4 gates), 128x128 tiles
    {
        GemmB4 ga;
        for (int g = 0; g < 4; ++g) { ga.A[g] = wX; ga.Bt[g] = wVt[g]; ga.bias[g] = iVb[g]; ga.C[g] = bufA[g]; }
        gemm_k<<<dim3(4, 15, 4), 256, 0, stream>>>(ga, B_ * T_, FD_, E_, 304, 304, 0, 0, 0);
    }
    {
        GemmB4 ga;
        for (int g = 0; g < 4; ++g) { ga.A[g] = bufA[g]; ga.Bt[g] = wSt[g]; ga.bias[g] = iSb[g]; ga.C[g] = bufB[g]; }
        gemm_k<<<dim3(4, 15, 4), 256, 0, stream>>>(ga, B_ * T_, FD_, FD_, FD_, FD_, 0, 0, 0);
    }
    {
        GemmB4 ga;
        for (int g = 0; g < 4; ++g) { ga.A[g] = bufB[g]; ga.Bt[g] = wUt[g]; ga.bias[g] = iUb[g]; ga.C[g] = bufA[g]; }
        gemm_k<<<dim3(4, 15, 4), 256, 0, stream>>>(ga, B_ * T_, H_, FD_, FD_, FD_, 0, 0, 0);
    }

    // ---- fused 30-step LSTM (single launch, grid barrier per step)
    {
        FusedA fa;
        fa.h0 = cH0;
        for (int g = 0; g < 4; ++g) {
            fa.Wt[g] = wWt[g];
            fa.Wb[g] = iWb[g];
            fa.U[g] = bufA[g];
        }
        fa.c0 = c0;
        fa.Hall = Hall;
        fa.bar = dbar;
        lstm_fused<<<dim3(NWG_FUSED), 256, 0, stream>>>(fa);
    }

    // ---- vocab projection for all (t,b), f32 output, permuting rows back to [B][T][V]
    {
        GemmB4 ga{};
        ga.A[0] = Hall; ga.Bt[0] = wCt; ga.bias[0] = Cb; ga.C[0] = d_out;
        gemm_k<<<dim3(79, 15, 1), 256, 0, stream>>>(
            ga, B_ * T_, V_, H_, H_, H_, B_, T_, 1);
    }
}